// Round 5
// baseline (212.890 us; speedup 1.0000x reference)
//
#include <hip/hip_runtime.h>
#include <hip/hip_bf16.h>

// SimilarityPreserving loss, O(b*d^2) factorization (b=8192, d=128):
//   loss = (1/b^2) * sum_i 2*(1 - rho_i),  rho_i = C_i / sqrt(A_i*B_i)
//   A_i = xt_i^T Gt xt_i,  Gt = Yt_hat^T Yt_hat   (Yt_hat = row-normalized zyt)
//   B_i = xs_i^T Gs xs_i,  Gs = Ys_hat^T Ys_hat
//   C_i = xt_i^T M  xs_i,  M  = Yt_hat^T Ys_hat
// X normalization and temperature fold out of rho (scale invariance); eps
// terms never bind. Total ~1.6 GFLOP vs 34.4 GFLOP for the O(b^2 d) gram.
// Error budget: tolerance on mean(rho) is +-0.02; bf16 MFMA gives ~1e-4.

typedef __attribute__((ext_vector_type(8))) short short8;   // 8 bf16
typedef __attribute__((ext_vector_type(4))) float float4v;  // MFMA C/D

#define BSZ 8192
#define DIM 128
#define NP  64          // split-K partial blocks in gram_g
#define PITCH 72        // LDS transposed-tile pitch (16B-multiple, breaks row aliasing)
#define INV_B2 1.4901161193847656e-08f  // 1/8192^2

__device__ __forceinline__ short f2bf(float x) {
    union { __hip_bfloat16 b; short s; } u;
    u.b = __float2bfloat16(x);
    return u.s;
}

// ---------------------------------------------------------------- stage 1
// Gt, Gs, M (128x128 each) via split-K: block handles K-rows [blk*128,+128).
// Per block: compute row norms of its Y rows, stage normalized bf16 tiles
// TRANSPOSED (k-major) in LDS, 16x16x32 MFMA over 8x8 tile grid x 3 grams,
// write fp32 partial [blk][3][128][128].
__global__ __launch_bounds__(256) void gram_g(
    const float* __restrict__ Yt, const float* __restrict__ Ys,
    float* __restrict__ partial)
{
    __shared__ short T[2][128 * PITCH];   // [mat][d*PITCH + k], 36 KB
    __shared__ float invn[2][128];

    const int tid  = threadIdx.x;
    const int lane = tid & 63;
    const int wave = tid >> 6;   // 0..3
    const int q    = lane >> 4;
    const int l15  = lane & 15;
    const int blk  = blockIdx.x; // 0..63

    const float* Ym[2] = {Yt, Ys};

    // ---- norms: wave w -> mat w>>1, local rows (w&1)*64..+64, 2 rows/iter
    {
        int m = wave >> 1, rb = (wave & 1) * 64;
        const float* Y = Ym[m];
        int half = lane >> 5, c = lane & 31;
        for (int it = 0; it < 32; ++it) {
            int r = rb + it * 2 + half;
            const float4* rp = (const float4*)(Y + (size_t)(blk * 128 + r) * DIM);
            float4 v = rp[c];
            float ss = v.x * v.x + v.y * v.y + v.z * v.z + v.w * v.w;
            #pragma unroll
            for (int off = 1; off < 32; off <<= 1) ss += __shfl_xor(ss, off);
            if (c == 0) invn[m][r] = (ss > 0.f) ? rsqrtf(ss) : 0.f;
        }
    }
    __syncthreads();

    // acc tiles: wave owns Gt row-strips {2w,2w+1}, Gs col-strips {2w,2w+1},
    // M row-strips {2w,2w+1}: 48 tiles = 192 VGPR (1 wave/SIMD, fine).
    float4v gt[2][8], gs[8][2], gm[2][8];
    #pragma unroll
    for (int a = 0; a < 2; ++a)
        #pragma unroll
        for (int b = 0; b < 8; ++b) {
            gt[a][b] = (float4v){0.f, 0.f, 0.f, 0.f};
            gm[a][b] = gt[a][b];
            gs[b][a] = gt[a][b];
        }

    const int m_ = wave & 1, h = wave >> 1;   // staging role
    const float* Ystage = Ym[m_];

    for (int c = 0; c < 2; ++c) {   // two 64-k-row chunks
        if (c) __syncthreads();
        // ---- stage transposed: lane -> d = h*64+lane; 64 j-rows
        {
            float invl = invn[m_][c * 64 + lane];   // invnorm for j-local c*64+lane
            short* Tm = T[m_];
            int d = h * 64 + lane;
            const float* base = Ystage + (size_t)(blk * 128 + c * 64) * DIM + d;
            #pragma unroll
            for (int g8 = 0; g8 < 8; ++g8) {
                short8 buf;
                #pragma unroll
                for (int ii = 0; ii < 8; ++ii) {
                    int i = g8 * 8 + ii;
                    float sc = __shfl(invl, i);          // invnorm of row j=i
                    float v  = base[(size_t)i * DIM] * sc;
                    buf[ii] = f2bf(v);
                }
                *(short8*)&Tm[d * PITCH + g8 * 8] = buf;  // 16B aligned
            }
        }
        __syncthreads();

        // ---- MFMA: 2 ksteps of 32; frag layout A==B (lane holds 8 k at d=l15)
        #pragma unroll
        for (int kk = 0; kk < 2; ++kk) {
            short8 Ft[8], Fs[8];
            #pragma unroll
            for (int s = 0; s < 8; ++s) {
                int off = (s * 16 + l15) * PITCH + kk * 32 + q * 8;
                Ft[s] = *(const short8*)&T[0][off];
                Fs[s] = *(const short8*)&T[1][off];
            }
            #pragma unroll
            for (int b = 0; b < 8; ++b) {
                #pragma unroll
                for (int ri = 0; ri < 2; ++ri) {
                    gt[ri][b] = __builtin_amdgcn_mfma_f32_16x16x32_bf16(
                        Ft[2 * wave + ri], Ft[b], gt[ri][b], 0, 0, 0);
                    gm[ri][b] = __builtin_amdgcn_mfma_f32_16x16x32_bf16(
                        Ft[2 * wave + ri], Fs[b], gm[ri][b], 0, 0, 0);
                    gs[b][ri] = __builtin_amdgcn_mfma_f32_16x16x32_bf16(
                        Fs[b], Fs[2 * wave + ri], gs[b][ri], 0, 0, 0);
                }
            }
        }
    }

    // ---- store partials. D tile: row = q*4+r, col = l15.
    float* P = partial + (size_t)blk * 3 * 16384;
    #pragma unroll
    for (int ri = 0; ri < 2; ++ri)
        #pragma unroll
        for (int b = 0; b < 8; ++b)
            #pragma unroll
            for (int r = 0; r < 4; ++r) {
                int d1 = (2 * wave + ri) * 16 + q * 4 + r;
                int d2 = b * 16 + l15;
                P[(d1 << 7) + d2]             = gt[ri][b][r];
                P[2 * 16384 + (d1 << 7) + d2] = gm[ri][b][r];
                int e1 = b * 16 + q * 4 + r;               // Gs tile (b, 2w+ri)
                int e2 = (2 * wave + ri) * 16 + l15;
                P[16384 + (e1 << 7) + e2]     = gs[b][ri][r];
            }
}

// ---------------------------------------------------------------- stage 2
// Sum NP partials -> Gb[g][d2][d1] bf16 (TRANSPOSED so quad's B-fragments
// are contiguous 16B loads: lane needs 8 consecutive d1 at fixed d2).
__global__ __launch_bounds__(256) void reduce_g(
    const float* __restrict__ partial, __hip_bfloat16* __restrict__ Gb)
{
    int o = blockIdx.x * 256 + threadIdx.x;   // < 3*16384
    int g = o >> 14, rem = o & 16383;
    float s = 0.f;
    for (int b = 0; b < NP; ++b)
        s += partial[((size_t)(b * 3 + g) << 14) + rem];
    int d1 = rem >> 7, d2 = rem & 127;
    Gb[(g << 14) + (d2 << 7) + d1] = __float2bfloat16(s);
}

// ---------------------------------------------------------------- stage 3
// Per row i: Q = x^T G via MFMA, fold Q.x -> A,B,C; rho; atomicAdd loss.
// Raw fp32 X (normalization folds out of rho). 128 blocks x 4 waves x 16 rows.
__global__ __launch_bounds__(256) void quad_k(
    const float* __restrict__ Xt, const float* __restrict__ Xs,
    const __hip_bfloat16* __restrict__ Gb, float* __restrict__ out)
{
    const int tid  = threadIdx.x;
    const int lane = tid & 63;
    const int wave = tid >> 6;
    const int q    = lane >> 4;
    const int l15  = lane & 15;
    const int rbase = blockIdx.x * 64 + wave * 16;

    // A-frags: lane holds X[rbase+l15][kk*32+q*8 ..+8) as bf16
    short8 At[4], As[4];
    #pragma unroll
    for (int kk = 0; kk < 4; ++kk) {
        const float* pt = Xt + (size_t)(rbase + l15) * DIM + kk * 32 + q * 8;
        const float* ps = Xs + (size_t)(rbase + l15) * DIM + kk * 32 + q * 8;
        float4 t0 = *(const float4*)pt, t1 = *(const float4*)(pt + 4);
        float4 s0 = *(const float4*)ps, s1 = *(const float4*)(ps + 4);
        short8 a, b;
        a[0]=f2bf(t0.x); a[1]=f2bf(t0.y); a[2]=f2bf(t0.z); a[3]=f2bf(t0.w);
        a[4]=f2bf(t1.x); a[5]=f2bf(t1.y); a[6]=f2bf(t1.z); a[7]=f2bf(t1.w);
        b[0]=f2bf(s0.x); b[1]=f2bf(s0.y); b[2]=f2bf(s0.z); b[3]=f2bf(s0.w);
        b[4]=f2bf(s1.x); b[5]=f2bf(s1.y); b[6]=f2bf(s1.z); b[7]=f2bf(s1.w);
        At[kk] = a; As[kk] = b;
    }

    float fA[4] = {0,0,0,0}, fB[4] = {0,0,0,0}, fC[4] = {0,0,0,0};
    const short* G = (const short*)Gb;

    #pragma unroll
    for (int nt = 0; nt < 8; ++nt) {
        int d2 = nt * 16 + l15;
        float4v qt = {0.f,0.f,0.f,0.f}, qs = qt, qc = qt;
        #pragma unroll
        for (int kk = 0; kk < 4; ++kk) {
            int off = (d2 << 7) + kk * 32 + q * 8;
            short8 Bt = *(const short8*)&G[off];
            short8 Bs = *(const short8*)&G[16384 + off];
            short8 Bm = *(const short8*)&G[32768 + off];
            qt = __builtin_amdgcn_mfma_f32_16x16x32_bf16(At[kk], Bt, qt, 0, 0, 0);
            qs = __builtin_amdgcn_mfma_f32_16x16x32_bf16(As[kk], Bs, qs, 0, 0, 0);
            qc = __builtin_amdgcn_mfma_f32_16x16x32_bf16(At[kk], Bm, qc, 0, 0, 0);
        }
        // fold: D row = q*4+r, col = l15 -> Q[row][d2]; A += Q*xt, etc.
        #pragma unroll
        for (int r = 0; r < 4; ++r) {
            int row = rbase + q * 4 + r;
            float xtv = Xt[(size_t)row * DIM + d2];
            float xsv = Xs[(size_t)row * DIM + d2];
            fA[r] += qt[r] * xtv;
            fB[r] += qs[r] * xsv;
            fC[r] += qc[r] * xsv;
        }
    }

    float wl = 0.f;
    #pragma unroll
    for (int r = 0; r < 4; ++r) {
        float A = fA[r], B = fB[r], C = fC[r];
        #pragma unroll
        for (int off = 1; off < 16; off <<= 1) {
            A += __shfl_xor(A, off);
            B += __shfl_xor(B, off);
            C += __shfl_xor(C, off);
        }
        float contrib = 2.f - 2.f * C * rsqrtf(A * B);
        wl += (l15 == 0) ? contrib : 0.f;
    }
    wl += __shfl_xor(wl, 16);
    wl += __shfl_xor(wl, 32);

    __shared__ float wred[4];
    if (lane == 0) wred[wave] = wl;
    __syncthreads();
    if (tid == 0)
        atomicAdd(out, (wred[0] + wred[1] + wred[2] + wred[3]) * INV_B2);
}

// ---------------------------------------------------------------- launch
extern "C" void kernel_launch(void* const* d_in, const int* in_sizes, int n_in,
                              void* d_out, int out_size, void* d_ws, size_t ws_size,
                              hipStream_t stream) {
    const float* zxs = (const float*)d_in[0];
    const float* zys = (const float*)d_in[1];
    const float* zxt = (const float*)d_in[2];
    const float* zyt = (const float*)d_in[3];
    // d_in[4] = temperature: folds out of rho, unused.
    float* out = (float*)d_out;

    char* ws = (char*)d_ws;
    float* partial = (float*)ws;                                  // NP*3*16384 fp32 = 12.6 MB
    __hip_bfloat16* Gb = (__hip_bfloat16*)(ws + (size_t)NP * 3 * 16384 * sizeof(float));

    hipMemsetAsync(out, 0, sizeof(float), stream);
    gram_g  <<<NP,  256, 0, stream>>>(zyt, zys, partial);
    reduce_g<<<192, 256, 0, stream>>>(partial, Gb);
    quad_k  <<<128, 256, 0, stream>>>(zxt, zxs, Gb, out);
}

// Round 6
// 112.721 us; speedup vs baseline: 1.8887x; 1.8887x over previous
//
#include <hip/hip_runtime.h>
#include <hip/hip_bf16.h>

// SimilarityPreserving loss, O(b*d^2) factorization (b=8192, d=128):
//   loss = (1/b^2) * sum_i 2*(1 - rho_i),  rho_i = C_i / sqrt(A_i*B_i)
//   A_i = xt_i^T Gt xt_i,  Gt = Yt_hat^T Yt_hat  (Yt_hat = row-normalized zyt)
//   B_i = xs_i^T Gs xs_i,  Gs = Ys_hat^T Ys_hat
//   C_i = xt_i^T M  xs_i,  M  = Yt_hat^T Ys_hat
// X normalization and temperature fold out of rho (scale invariance); eps
// never binds. Math verified in R5 (absmax 0.0).
//
// R6 rebuild of stage 1 (R5 post-mortem: 48 acc tiles = 192 VGPR -> spills,
// 64 blocks -> 3% occupancy, 129 us):
//  - one gram per block: grid = NP k-splits x 3 grams = 384 blocks,
//    per-wave acc = 16 tiles = 64 VGPR, launch_bounds(256,3), no spills.
//  - staging reads Y once into registers (32 in-flight coalesced dwords),
//    cross-wave row norms via shfl+LDS, aligned b128 transposed stores at
//    PITCH=72 shorts (144 B stride -> 2-way bank aliasing = free, 16B align).

typedef __attribute__((ext_vector_type(8))) short short8;   // 8 bf16
typedef __attribute__((ext_vector_type(4))) float float4v;  // MFMA C/D

#define BSZ 8192
#define DIM 128
#define NP  128          // k-splits per gram
#define KROWS 64         // Y rows per block
#define PITCH 72         // shorts per d-row of T (64 k + 8 pad; 144 B, 16B-aligned)
#define INV_B2 1.4901161193847656e-08f  // 1/8192^2

__device__ __forceinline__ short f2bf(float x) {
    union { __hip_bfloat16 b; short s; } u;
    u.b = __float2bfloat16(x);
    return u.s;
}

// ---------------------------------------------------------------- stage 1
// Block (split, gram): partial G for k-rows [split*64, +64) of ONE gram.
__global__ __launch_bounds__(256, 3) void gram_g(
    const float* __restrict__ Yt, const float* __restrict__ Ys,
    float* __restrict__ partial)
{
    __shared__ short T[2][128 * PITCH];   // [mat][d*PITCH + k], 36 KB
    __shared__ float rsum[2][KROWS];      // per-row partial sums (2 d-halves)
    __shared__ float invn[KROWS];

    const int tid   = threadIdx.x;
    const int lane  = tid & 63;
    const int wave  = tid >> 6;     // 0..3
    const int d     = tid & 127;    // column owned for staging
    const int khalf = tid >> 7;     // 0/1: which 32-row half
    const int q     = lane >> 4;
    const int l15   = lane & 15;
    const int split = blockIdx.x;   // 0..NP-1
    const int gram  = blockIdx.y;   // 0=Gt 1=Gs 2=M

    // ---- stage one mat into T[m]: load 32 col-elements/thread (coalesced,
    // all in flight), row norms, normalized bf16 transposed store.
    auto stage_mat = [&](int m, const float* __restrict__ Y) {
        float v[32];
        const float* base = Y + ((size_t)(split * KROWS + khalf * 32)) * DIM + d;
        #pragma unroll
        for (int i = 0; i < 32; ++i) v[i] = base[(size_t)i * DIM];

        #pragma unroll
        for (int i = 0; i < 32; ++i) {
            float ss = v[i] * v[i];
            #pragma unroll
            for (int off = 1; off < 64; off <<= 1) ss += __shfl_xor(ss, off);
            if (lane == 0) rsum[wave & 1][khalf * 32 + i] = ss;
        }
        __syncthreads();
        if (tid < KROWS) {
            float s = rsum[0][tid] + rsum[1][tid];
            invn[tid] = (s > 0.f) ? rsqrtf(s) : 0.f;
        }
        __syncthreads();

        #pragma unroll
        for (int g = 0; g < 4; ++g) {
            short8 pk;
            #pragma unroll
            for (int j = 0; j < 8; ++j) {
                int i = g * 8 + j;
                pk[j] = f2bf(v[i] * invn[khalf * 32 + i]);  // LDS broadcast
            }
            *(short8*)&T[m][d * PITCH + khalf * 32 + g * 8] = pk;
        }
    };

    if (gram == 0) {
        stage_mat(0, Yt);
    } else if (gram == 1) {
        stage_mat(0, Ys);
    } else {
        stage_mat(0, Yt);
        __syncthreads();   // invn reuse: separate mat-0 readers from mat-1 writers
        stage_mat(1, Ys);
    }
    __syncthreads();

    const short* TA = T[0];
    const short* TB = (gram == 2) ? T[1] : T[0];

    // ---- MFMA: wave owns d1-strips {2w, 2w+1}; 2 ksteps of 32.
    // A and B share the same fragment layout here (lane holds 8 k at d=l15):
    // A[m=l15][k=q*8+j] = Yhat[k][d1], B[k=q*8+j][n=l15] = Yhat[k][d2].
    float4v acc[2][8];
    #pragma unroll
    for (int a = 0; a < 2; ++a)
        #pragma unroll
        for (int b = 0; b < 8; ++b) acc[a][b] = (float4v){0.f, 0.f, 0.f, 0.f};

    #pragma unroll
    for (int kk = 0; kk < 2; ++kk) {
        short8 fb[8], fa[2];
        #pragma unroll
        for (int s = 0; s < 8; ++s)
            fb[s] = *(const short8*)&TB[(s * 16 + l15) * PITCH + kk * 32 + q * 8];
        #pragma unroll
        for (int a = 0; a < 2; ++a)
            fa[a] = *(const short8*)&TA[((wave * 2 + a) * 16 + l15) * PITCH + kk * 32 + q * 8];
        #pragma unroll
        for (int a = 0; a < 2; ++a)
            #pragma unroll
            for (int b = 0; b < 8; ++b)
                acc[a][b] = __builtin_amdgcn_mfma_f32_16x16x32_bf16(
                    fa[a], fb[b], acc[a][b], 0, 0, 0);
    }

    // ---- store partial slab. D tile: d1 = strip*16 + q*4 + r, d2 = b*16+l15.
    float* P = partial + ((size_t)(gram * NP + split) << 14);
    #pragma unroll
    for (int a = 0; a < 2; ++a) {
        int strip = wave * 2 + a;
        #pragma unroll
        for (int b = 0; b < 8; ++b)
            #pragma unroll
            for (int r = 0; r < 4; ++r)
                P[((strip * 16 + q * 4 + r) << 7) + b * 16 + l15] = acc[a][b][r];
    }
}

// ---------------------------------------------------------------- stage 2
// Sum NP partials -> Gb[g][d2][d1] bf16 (transposed so quad_k's B-fragments
// are contiguous 16B loads).
__global__ __launch_bounds__(256) void reduce_g(
    const float* __restrict__ partial, __hip_bfloat16* __restrict__ Gb)
{
    int o = blockIdx.x * 256 + threadIdx.x;   // < 3*16384
    int g = o >> 14, rem = o & 16383;
    float s = 0.f;
    for (int b = 0; b < NP; ++b)
        s += partial[((size_t)(g * NP + b) << 14) + rem];
    int d1 = rem >> 7, d2 = rem & 127;
    Gb[(g << 14) + (d2 << 7) + d1] = __float2bfloat16(s);
}

// ---------------------------------------------------------------- stage 3
// Per row i: Q = x^T G via MFMA, fold Q.x -> A,B,C; rho; atomicAdd loss.
// Raw fp32 X (normalization folds out of rho). 128 blocks x 4 waves x 16 rows.
__global__ __launch_bounds__(256) void quad_k(
    const float* __restrict__ Xt, const float* __restrict__ Xs,
    const __hip_bfloat16* __restrict__ Gb, float* __restrict__ out)
{
    const int tid  = threadIdx.x;
    const int lane = tid & 63;
    const int wave = tid >> 6;
    const int q    = lane >> 4;
    const int l15  = lane & 15;
    const int rbase = blockIdx.x * 64 + wave * 16;

    // A-frags: lane holds X[rbase+l15][kk*32+q*8 ..+8) as bf16
    short8 At[4], As[4];
    #pragma unroll
    for (int kk = 0; kk < 4; ++kk) {
        const float* pt = Xt + (size_t)(rbase + l15) * DIM + kk * 32 + q * 8;
        const float* ps = Xs + (size_t)(rbase + l15) * DIM + kk * 32 + q * 8;
        float4 t0 = *(const float4*)pt, t1 = *(const float4*)(pt + 4);
        float4 s0 = *(const float4*)ps, s1 = *(const float4*)(ps + 4);
        short8 a, b;
        a[0]=f2bf(t0.x); a[1]=f2bf(t0.y); a[2]=f2bf(t0.z); a[3]=f2bf(t0.w);
        a[4]=f2bf(t1.x); a[5]=f2bf(t1.y); a[6]=f2bf(t1.z); a[7]=f2bf(t1.w);
        b[0]=f2bf(s0.x); b[1]=f2bf(s0.y); b[2]=f2bf(s0.z); b[3]=f2bf(s0.w);
        b[4]=f2bf(s1.x); b[5]=f2bf(s1.y); b[6]=f2bf(s1.z); b[7]=f2bf(s1.w);
        At[kk] = a; As[kk] = b;
    }

    float fA[4] = {0,0,0,0}, fB[4] = {0,0,0,0}, fC[4] = {0,0,0,0};
    const short* G = (const short*)Gb;

    #pragma unroll
    for (int nt = 0; nt < 8; ++nt) {
        int d2 = nt * 16 + l15;
        float4v qt = {0.f,0.f,0.f,0.f}, qs = qt, qc = qt;
        #pragma unroll
        for (int kk = 0; kk < 4; ++kk) {
            int off = (d2 << 7) + kk * 32 + q * 8;
            short8 Bt = *(const short8*)&G[off];
            short8 Bs = *(const short8*)&G[16384 + off];
            short8 Bm = *(const short8*)&G[32768 + off];
            qt = __builtin_amdgcn_mfma_f32_16x16x32_bf16(At[kk], Bt, qt, 0, 0, 0);
            qs = __builtin_amdgcn_mfma_f32_16x16x32_bf16(As[kk], Bs, qs, 0, 0, 0);
            qc = __builtin_amdgcn_mfma_f32_16x16x32_bf16(At[kk], Bm, qc, 0, 0, 0);
        }
        // fold: D row = q*4+r, col = l15 -> Q[row][d2]; A += Q*x, etc.
        #pragma unroll
        for (int r = 0; r < 4; ++r) {
            int row = rbase + q * 4 + r;
            float xtv = Xt[(size_t)row * DIM + d2];
            float xsv = Xs[(size_t)row * DIM + d2];
            fA[r] += qt[r] * xtv;
            fB[r] += qs[r] * xsv;
            fC[r] += qc[r] * xsv;
        }
    }

    float wl = 0.f;
    #pragma unroll
    for (int r = 0; r < 4; ++r) {
        float A = fA[r], B = fB[r], C = fC[r];
        #pragma unroll
        for (int off = 1; off < 16; off <<= 1) {
            A += __shfl_xor(A, off);
            B += __shfl_xor(B, off);
            C += __shfl_xor(C, off);
        }
        float contrib = 2.f - 2.f * C * rsqrtf(A * B);
        wl += (l15 == 0) ? contrib : 0.f;
    }
    wl += __shfl_xor(wl, 16);
    wl += __shfl_xor(wl, 32);

    __shared__ float wred[4];
    if (lane == 0) wred[wave] = wl;
    __syncthreads();
    if (tid == 0)
        atomicAdd(out, (wred[0] + wred[1] + wred[2] + wred[3]) * INV_B2);
}

// ---------------------------------------------------------------- launch
extern "C" void kernel_launch(void* const* d_in, const int* in_sizes, int n_in,
                              void* d_out, int out_size, void* d_ws, size_t ws_size,
                              hipStream_t stream) {
    const float* zxs = (const float*)d_in[0];
    const float* zys = (const float*)d_in[1];
    const float* zxt = (const float*)d_in[2];
    const float* zyt = (const float*)d_in[3];
    // d_in[4] = temperature: folds out of rho, unused.
    float* out = (float*)d_out;

    char* ws = (char*)d_ws;
    float* partial = (float*)ws;   // 3*NP*16384 fp32 = 25.2 MB
    __hip_bfloat16* Gb = (__hip_bfloat16*)(ws + (size_t)3 * NP * 16384 * sizeof(float));

    hipMemsetAsync(out, 0, sizeof(float), stream);
    dim3 ggrid(NP, 3);
    gram_g  <<<ggrid, 256, 0, stream>>>(zyt, zys, partial);
    reduce_g<<<192,   256, 0, stream>>>(partial, Gb);
    quad_k  <<<128,   256, 0, stream>>>(zxt, zxs, Gb, out);
}

// Round 7
// 109.095 us; speedup vs baseline: 1.9514x; 1.0332x over previous
//
#include <hip/hip_runtime.h>
#include <hip/hip_bf16.h>

// SimilarityPreserving loss, O(b*d^2) factorization (b=8192, d=128):
//   loss = (1/b^2) * sum_i 2*(1 - rho_i),  rho_i = C_i / sqrt(A_i*B_i)
//   A_i = xt_i^T Gt xt_i,  Gt = Yt_hat^T Yt_hat  (Yt_hat = row-normalized zyt)
//   B_i = xs_i^T Gs xs_i,  Gs = Ys_hat^T Ys_hat
//   C_i = xt_i^T M  xs_i,  M  = Yt_hat^T Ys_hat
// X normalization and temperature fold out of rho (scale invariance); eps
// never binds. Math verified R5/R6 (absmax 0.0).
//
// R7 (post-mortem of R6: gram_g's in-block norm shfl-storm ran 4x redundantly
// and the fp32 partial slab round-tripped 50 MB):
//  - prep: norms computed ONCE; writes Yhat TRANSPOSED bf16 [mat][d][8192].
//    Transposed store is per-thread contiguous (thread owns column d). Also
//    zeroes out -> memset dispatch gone.
//  - gram_g: NO LDS, NO barriers — A/B fragments are direct contiguous 16B
//    global loads from Yhat_T. 512-thr blocks, 1 d1-strip per wave,
//    NP=64 k-splits (K=128/block) -> 12.6 MB partial slab (was 25.2).
//  - reduce_g / quad_k unchanged in structure (verified).

typedef __attribute__((ext_vector_type(8))) short short8;   // 8 bf16
typedef __attribute__((ext_vector_type(4))) float float4v;  // MFMA C/D

#define BSZ 8192
#define DIM 128
#define NP  64           // k-splits per gram (K=128 each)
#define INV_B2 1.4901161193847656e-08f  // 1/8192^2

__device__ __forceinline__ short f2bf(float x) {
    union { __hip_bfloat16 b; short s; } u;
    u.b = __float2bfloat16(x);
    return u.s;
}

// ---------------------------------------------------------------- stage 0
// prep: block (chunk, mat) normalizes 64 rows of one Y and writes them
// TRANSPOSED bf16 into YT[mat][d][8192]. Thread owns column d for 32 rows:
// loads are coalesced (512B/row-instr), transposed stores are per-thread
// contiguous 64 B. Norms: 64-lane shfl + 2-half LDS combine (once per row).
__global__ __launch_bounds__(256) void prep(
    const float* __restrict__ Yt, const float* __restrict__ Ys,
    short* __restrict__ YT, float* __restrict__ out)
{
    __shared__ float rsum[2][64];
    __shared__ float invn[64];

    const int tid   = threadIdx.x;
    const int lane  = tid & 63;
    const int wave  = tid >> 6;     // 0..3; wave&1 = d-half
    const int d     = tid & 127;
    const int khalf = tid >> 7;     // 0/1: row half
    const int chunk = blockIdx.x;   // 0..127
    const int mat   = blockIdx.y;   // 0..1
    const float* Y  = mat ? Ys : Yt;

    if (chunk == 0 && mat == 0 && tid == 0) out[0] = 0.f;

    float v[32];
    const float* base = Y + (size_t)(chunk * 64 + khalf * 32) * DIM + d;
    #pragma unroll
    for (int i = 0; i < 32; ++i) v[i] = base[(size_t)i * DIM];

    #pragma unroll
    for (int i = 0; i < 32; ++i) {
        float ss = v[i] * v[i];
        #pragma unroll
        for (int off = 1; off < 64; off <<= 1) ss += __shfl_xor(ss, off);
        if (lane == 0) rsum[wave & 1][khalf * 32 + i] = ss;
    }
    __syncthreads();
    if (tid < 64) {
        float s = rsum[0][tid] + rsum[1][tid];
        invn[tid] = (s > 0.f) ? rsqrtf(s) : 0.f;
    }
    __syncthreads();

    short* yt = YT + ((size_t)mat * 128 + d) * BSZ + chunk * 64 + khalf * 32;
    #pragma unroll
    for (int g = 0; g < 4; ++g) {
        short8 pk;
        #pragma unroll
        for (int j = 0; j < 8; ++j) {
            int i = g * 8 + j;
            pk[j] = f2bf(v[i] * invn[khalf * 32 + i]);
        }
        *(short8*)&yt[g * 8] = pk;
    }
}

// ---------------------------------------------------------------- stage 1
// Block (split, gram): fp32 partial G over k-rows [split*128, +128).
// 8 waves, wave = d1-strip. Fragments load straight from YT (contiguous 16B
// per lane; per instr 16 rows x 64 B segments). 32 MFMA/wave, no LDS.
__global__ __launch_bounds__(512) void gram_g(
    const short* __restrict__ YT, float* __restrict__ partial)
{
    const int tid  = threadIdx.x;
    const int lane = tid & 63;
    const int s1   = tid >> 6;    // wave = d1 strip 0..7
    const int q    = lane >> 4;
    const int l15  = lane & 15;
    const int split = blockIdx.x; // 0..NP-1
    const int gram  = blockIdx.y; // 0=Gt 1=Gs 2=M

    const short* Ta = (gram == 1) ? YT + (size_t)128 * BSZ : YT;  // Gs->Ys
    const short* Tb = (gram == 0) ? YT : YT + (size_t)128 * BSZ;  // Gt->Yt
    const int k0 = split * 128;

    float4v acc[8];
    #pragma unroll
    for (int s2 = 0; s2 < 8; ++s2) acc[s2] = (float4v){0.f, 0.f, 0.f, 0.f};

    #pragma unroll
    for (int kk = 0; kk < 4; ++kk) {
        const int ko = k0 + kk * 32 + q * 8;
        short8 fa = *(const short8*)&Ta[(size_t)(s1 * 16 + l15) * BSZ + ko];
        short8 fb[8];
        #pragma unroll
        for (int s2 = 0; s2 < 8; ++s2)
            fb[s2] = *(const short8*)&Tb[(size_t)(s2 * 16 + l15) * BSZ + ko];
        #pragma unroll
        for (int s2 = 0; s2 < 8; ++s2)
            acc[s2] = __builtin_amdgcn_mfma_f32_16x16x32_bf16(fa, fb[s2], acc[s2], 0, 0, 0);
    }

    // D tile: d1 = s1*16 + q*4 + r, d2 = s2*16 + l15.
    float* P = partial + ((size_t)(gram * NP + split) << 14);
    #pragma unroll
    for (int s2 = 0; s2 < 8; ++s2)
        #pragma unroll
        for (int r = 0; r < 4; ++r)
            P[((s1 * 16 + q * 4 + r) << 7) + s2 * 16 + l15] = acc[s2][r];
}

// ---------------------------------------------------------------- stage 2
// Sum NP partials -> Gb[g][d2][d1] bf16 (transposed so quad_k's B-fragments
// are contiguous 16B loads).
__global__ __launch_bounds__(256) void reduce_g(
    const float* __restrict__ partial, __hip_bfloat16* __restrict__ Gb)
{
    int o = blockIdx.x * 256 + threadIdx.x;   // < 3*16384
    int g = o >> 14, rem = o & 16383;
    float s = 0.f;
    for (int b = 0; b < NP; ++b)
        s += partial[((size_t)(g * NP + b) << 14) + rem];
    int d1 = rem >> 7, d2 = rem & 127;
    Gb[(g << 14) + (d2 << 7) + d1] = __float2bfloat16(s);
}

// ---------------------------------------------------------------- stage 3
// Per row i: Q = x^T G via MFMA, fold Q.x -> A,B,C; rho; atomicAdd loss.
// Raw fp32 X (normalization folds out of rho). 128 blocks x 4 waves x 16 rows.
__global__ __launch_bounds__(256) void quad_k(
    const float* __restrict__ Xt, const float* __restrict__ Xs,
    const __hip_bfloat16* __restrict__ Gb, float* __restrict__ out)
{
    const int tid  = threadIdx.x;
    const int lane = tid & 63;
    const int wave = tid >> 6;
    const int q    = lane >> 4;
    const int l15  = lane & 15;
    const int rbase = blockIdx.x * 64 + wave * 16;

    // A-frags: lane holds X[rbase+l15][kk*32+q*8 ..+8) as bf16
    short8 At[4], As[4];
    #pragma unroll
    for (int kk = 0; kk < 4; ++kk) {
        const float* pt = Xt + (size_t)(rbase + l15) * DIM + kk * 32 + q * 8;
        const float* ps = Xs + (size_t)(rbase + l15) * DIM + kk * 32 + q * 8;
        float4 t0 = *(const float4*)pt, t1 = *(const float4*)(pt + 4);
        float4 s0 = *(const float4*)ps, s1 = *(const float4*)(ps + 4);
        short8 a, b;
        a[0]=f2bf(t0.x); a[1]=f2bf(t0.y); a[2]=f2bf(t0.z); a[3]=f2bf(t0.w);
        a[4]=f2bf(t1.x); a[5]=f2bf(t1.y); a[6]=f2bf(t1.z); a[7]=f2bf(t1.w);
        b[0]=f2bf(s0.x); b[1]=f2bf(s0.y); b[2]=f2bf(s0.z); b[3]=f2bf(s0.w);
        b[4]=f2bf(s1.x); b[5]=f2bf(s1.y); b[6]=f2bf(s1.z); b[7]=f2bf(s1.w);
        At[kk] = a; As[kk] = b;
    }

    float fA[4] = {0,0,0,0}, fB[4] = {0,0,0,0}, fC[4] = {0,0,0,0};
    const short* G = (const short*)Gb;

    #pragma unroll
    for (int nt = 0; nt < 8; ++nt) {
        int d2 = nt * 16 + l15;
        float4v qt = {0.f,0.f,0.f,0.f}, qs = qt, qc = qt;
        #pragma unroll
        for (int kk = 0; kk < 4; ++kk) {
            int off = (d2 << 7) + kk * 32 + q * 8;
            short8 Bt = *(const short8*)&G[off];
            short8 Bs = *(const short8*)&G[16384 + off];
            short8 Bm = *(const short8*)&G[32768 + off];
            qt = __builtin_amdgcn_mfma_f32_16x16x32_bf16(At[kk], Bt, qt, 0, 0, 0);
            qs = __builtin_amdgcn_mfma_f32_16x16x32_bf16(As[kk], Bs, qs, 0, 0, 0);
            qc = __builtin_amdgcn_mfma_f32_16x16x32_bf16(At[kk], Bm, qc, 0, 0, 0);
        }
        // fold: D row = q*4+r, col = l15 -> Q[row][d2]; A += Q*x, etc.
        #pragma unroll
        for (int r = 0; r < 4; ++r) {
            int row = rbase + q * 4 + r;
            float xtv = Xt[(size_t)row * DIM + d2];
            float xsv = Xs[(size_t)row * DIM + d2];
            fA[r] += qt[r] * xtv;
            fB[r] += qs[r] * xsv;
            fC[r] += qc[r] * xsv;
        }
    }

    float wl = 0.f;
    #pragma unroll
    for (int r = 0; r < 4; ++r) {
        float A = fA[r], B = fB[r], C = fC[r];
        #pragma unroll
        for (int off = 1; off < 16; off <<= 1) {
            A += __shfl_xor(A, off);
            B += __shfl_xor(B, off);
            C += __shfl_xor(C, off);
        }
        float contrib = 2.f - 2.f * C * rsqrtf(A * B);
        wl += (l15 == 0) ? contrib : 0.f;
    }
    wl += __shfl_xor(wl, 16);
    wl += __shfl_xor(wl, 32);

    __shared__ float wred[4];
    if (lane == 0) wred[wave] = wl;
    __syncthreads();
    if (tid == 0)
        atomicAdd(out, (wred[0] + wred[1] + wred[2] + wred[3]) * INV_B2);
}

// ---------------------------------------------------------------- launch
extern "C" void kernel_launch(void* const* d_in, const int* in_sizes, int n_in,
                              void* d_out, int out_size, void* d_ws, size_t ws_size,
                              hipStream_t stream) {
    const float* zxs = (const float*)d_in[0];
    const float* zys = (const float*)d_in[1];
    const float* zxt = (const float*)d_in[2];
    const float* zyt = (const float*)d_in[3];
    // d_in[4] = temperature: folds out of rho, unused.
    float* out = (float*)d_out;

    char* ws = (char*)d_ws;
    short* YT = (short*)ws;                                    // 2 x 128 x 8192 bf16 = 4 MB
    float* partial = (float*)(ws + (size_t)4 * 1024 * 1024);   // 3*NP*16384 fp32 = 12.6 MB
    __hip_bfloat16* Gb = (__hip_bfloat16*)(ws + (size_t)4 * 1024 * 1024
                                              + (size_t)3 * NP * 16384 * sizeof(float));

    prep    <<<dim3(128, 2), 256, 0, stream>>>(zyt, zys, YT, out);
    gram_g  <<<dim3(NP, 3),  512, 0, stream>>>(YT, partial);
    reduce_g<<<192,          256, 0, stream>>>(partial, Gb);
    quad_k  <<<128,          256, 0, stream>>>(zxt, zxs, Gb, out);
}